// Round 1
// 628.895 us; speedup vs baseline: 1.2451x; 1.2451x over previous
//
#include <hip/hip_runtime.h>
#include <hip/hip_fp16.h>
#include <cfloat>
#include <climits>

// VectorQuantizer2: z [32,2048,256] fp32, codebook [4096,256] fp32.
#define D     256
#define NE    4096
#define MT    64       // rows per block (stageA)
#define BMT   128      // rows per block tile (stageB)
#define KT    128      // codes per k-tile (stageB)
#define DK    32       // d-chunk (stageB)
#define LDSP  132      // padded LDS leading dim (stageB)
#define NSPLIT 16      // stageB K-split factor
// DELTA covers worst-case np fp32 envelope (2*4.6e-5) + fp16 single-pass dot
// worst bound (~5e-5 score) + fp32 stageB error.
#define DELTA     1.5e-4f
#define CAND_CAP  131072

typedef _Float16 f16x8 __attribute__((ext_vector_type(8)));
typedef __attribute__((ext_vector_type(4))) float f32x4;

// ---------------------------------------------------------------------------
// numpy-bit-exact fp32 helpers. __fmul_rn/__fadd_rn are contraction barriers.
__device__ __forceinline__ float np_block128_sq(const float* __restrict__ p) {
    float r[8];
    #pragma unroll
    for (int j = 0; j < 8; ++j) r[j] = __fmul_rn(p[j], p[j]);
    #pragma unroll
    for (int i = 8; i < 128; i += 8)
        #pragma unroll
        for (int j = 0; j < 8; ++j) r[j] = __fadd_rn(r[j], __fmul_rn(p[i + j], p[i + j]));
    return __fadd_rn(__fadd_rn(__fadd_rn(r[0], r[1]), __fadd_rn(r[2], r[3])),
                     __fadd_rn(__fadd_rn(r[4], r[5]), __fadd_rn(r[6], r[7])));
}
__device__ __forceinline__ float np_sumsq256(const float* __restrict__ p) {
    return __fadd_rn(np_block128_sq(p), np_block128_sq(p + 128));
}
// np.einsum('nd,kd->nk', optimize=False) dot: SSE 4-lane, no FMA, 16/iter,
// chained muladd order p3,p2,p1,p0, SSE3 hadd (v0+v1)+(v2+v3).
__device__ __forceinline__ float np_einsum_dot256(const float* __restrict__ zr,
                                                  const float* __restrict__ er) {
    float v0 = 0.f, v1 = 0.f, v2 = 0.f, v3 = 0.f;
    for (int t = 0; t < 256; t += 16) {
        float4 a0 = *(const float4*)(zr + t);
        float4 a1 = *(const float4*)(zr + t + 4);
        float4 a2 = *(const float4*)(zr + t + 8);
        float4 a3 = *(const float4*)(zr + t + 12);
        float4 b0 = *(const float4*)(er + t);
        float4 b1 = *(const float4*)(er + t + 4);
        float4 b2 = *(const float4*)(er + t + 8);
        float4 b3 = *(const float4*)(er + t + 12);
        v0 = __fadd_rn(v0, __fmul_rn(a3.x, b3.x));
        v1 = __fadd_rn(v1, __fmul_rn(a3.y, b3.y));
        v2 = __fadd_rn(v2, __fmul_rn(a3.z, b3.z));
        v3 = __fadd_rn(v3, __fmul_rn(a3.w, b3.w));
        v0 = __fadd_rn(v0, __fmul_rn(a2.x, b2.x));
        v1 = __fadd_rn(v1, __fmul_rn(a2.y, b2.y));
        v2 = __fadd_rn(v2, __fmul_rn(a2.z, b2.z));
        v3 = __fadd_rn(v3, __fmul_rn(a2.w, b2.w));
        v0 = __fadd_rn(v0, __fmul_rn(a1.x, b1.x));
        v1 = __fadd_rn(v1, __fmul_rn(a1.y, b1.y));
        v2 = __fadd_rn(v2, __fmul_rn(a1.z, b1.z));
        v3 = __fadd_rn(v3, __fmul_rn(a1.w, b1.w));
        v0 = __fadd_rn(v0, __fmul_rn(a0.x, b0.x));
        v1 = __fadd_rn(v1, __fmul_rn(a0.y, b0.y));
        v2 = __fadd_rn(v2, __fmul_rn(a0.z, b0.z));
        v3 = __fadd_rn(v3, __fmul_rn(a0.w, b0.w));
    }
    return __fadd_rn(__fadd_rn(v0, v1), __fadd_rn(v2, v3));
}

// ---------------------------------------------------------------------------
// K1: Bnp[k] = np-exact sum(cb[k]**2)
__global__ void bnp_kernel(const float* __restrict__ cb, float* __restrict__ Bnp) {
    int k = blockIdx.x * 256 + threadIdx.x;
    if (k < NE) Bnp[k] = np_sumsq256(cb + (size_t)k * D);
}

// K2: fp32 -> fp16 (RNE), optional exact pow2 scale.
__global__ void tof16_kernel(const float* __restrict__ x,
                             unsigned short* __restrict__ y, float scale, int n4) {
    int t = blockIdx.x * 256 + threadIdx.x;
    if (t >= n4) return;
    float4 v = *(const float4*)(x + (size_t)t * 4);
    ushort4 o;
    o.x = __half_as_ushort(__float2half_rn(v.x * scale));
    o.y = __half_as_ushort(__float2half_rn(v.y * scale));
    o.z = __half_as_ushort(__float2half_rn(v.z * scale));
    o.w = __half_as_ushort(__float2half_rn(v.w * scale));
    *(ushort4*)(y + (size_t)t * 4) = o;
}

// direct global->LDS 16B (dwordx4). LDS dest must be wave-uniform base;
// HW writes lane i at base + 16*i. Global source is per-lane.
__device__ __forceinline__ void gload_lds16(const void* g, void* l) {
    __builtin_amdgcn_global_load_lds(
        (const __attribute__((address_space(1))) unsigned int*)g,
        (__attribute__((address_space(3))) unsigned int*)l, 16, 0, 0);
}

// ---------------------------------------------------------------------------
// K3 (stage A): single-pass fp16 MFMA score GEMM + per-row top-2.
// acc = z_f16 · (4096*cb)_f16 ;  s = Bnp[k] - 2^-11 * acc.
// Block: 256 thr = 4 waves (2x2), tile 64 rows x 128 codes, wave 32x64.
//   A panel: held ENTIRELY in registers (fa[8][2] f16x8 per thread, 64 VGPR),
//            loaded once from z2 -> zero A LDS traffic.
//   B tiles: 128 codes x 32 halves (8 KB) double-buffered in LDS, filled by
//            global_load_lds dwordx4 (no VGPR round-trip). Layout kc-major,
//            64B per code, bank-conflict broken by qd ^= (code>>1)&3 applied
//            on BOTH the (pre-swizzled) global source address and the
//            ds_read address (LDS dest of global_load_lds must stay linear).
//   Pipeline (T3-minimal): issue next tile's loads, compute current, ONE
//            __syncthreads per tile (its vmcnt(0) drain lands the prefetch).
//   Bnp is copied to LDS once so the epilogue has no VMEM.
__global__ __launch_bounds__(256, 3)
void stageA_f16(const unsigned short* __restrict__ z2,
                const unsigned short* __restrict__ cb2,
                const float* __restrict__ Bnp, int* __restrict__ idxArr,
                float* __restrict__ rowMin, unsigned long long* __restrict__ rowKey,
                int* __restrict__ flagCnt, int* __restrict__ flagList) {
    __shared__ unsigned char lds[32768];                 // 16K Bnp + 2x8K B dbuf
    float* BnpL = (float*)lds;
    unsigned short* Bt = (unsigned short*)(lds + 16384); // [2][4096] halves

    const int tid  = threadIdx.x;
    const int wid  = tid >> 6;
    const int lane = tid & 63;
    const int ln   = lane & 15;      // col within 16x16 tile
    const int qd   = lane >> 4;      // quad
    const int wm   = wid & 1;        // wave row (32 rows each)
    const int wn   = wid >> 1;       // wave col (64 codes each)
    const int R0   = blockIdx.x * MT;

    // ---- Bnp -> LDS (4096 f32, 4 float4 per thread)
    #pragma unroll
    for (int i = 0; i < 4; ++i) {
        int j = tid + 256 * i;
        *(float4*)(BnpL + j * 4) = *(const float4*)(Bnp + j * 4);
    }

    // ---- A panel -> registers: fa[kc][mt], fragment layout row=ln, k=qd*8..
    f16x8 fa[8][2];
    {
        const unsigned short* za = z2 + (size_t)(R0 + wm * 32 + ln) * 256 + qd * 8;
        #pragma unroll
        for (int kc = 0; kc < 8; ++kc)
            #pragma unroll
            for (int mt = 0; mt < 2; ++mt)
                fa[kc][mt] = *(const f16x8*)(za + mt * 16 * 256 + kc * 32);
    }

    // ---- B staging map: 2 x global_load_lds per wave per tile.
    // LDS slot s (16B) holds (code = s>>2, qslot = s&3); lane l of gll j
    // writes slot wid*128 + j*64 + l, so code = wid*32 + j*16 + (l>>2),
    // qslot = l&3. Pre-swizzled source segment = qslot ^ ((code>>1)&3).
    const int cA  = wid * 32 + (lane >> 2);
    const int cB  = cA + 16;
    const int sgA = (lane & 3) ^ ((cA >> 1) & 3);
    const int sgB = (lane & 3) ^ ((cB >> 1) & 3);
    const unsigned short* srcA = cb2 + cA * 256 + sgA * 8;
    const unsigned short* srcB = cb2 + cB * 256 + sgB * 8;
    unsigned short* dstA = Bt + wid * 1024;   // wave-uniform (bytes wid*2048)
    unsigned short* dstB = dstA + 512;

    // B fragment ds_read byte offset within one buffer (swizzled read side)
    const int boffs = ((wn * 64 + ln) << 6) + ((qd ^ ((ln >> 1) & 3)) << 4);
    const unsigned char* btb = (const unsigned char*)Bt;

    float best1[8], best2[8];
    int   bidx[8];
    #pragma unroll
    for (int i = 0; i < 8; ++i) { best1[i] = FLT_MAX; best2[i] = FLT_MAX; bidx[i] = 0; }

    // ---- prologue: stage tile (ct=0,kc=0) into buf 0
    gload_lds16(srcA, dstA);
    gload_lds16(srcB, dstB);
    __syncthreads();

    for (int ct = 0; ct < 32; ++ct) {
        f32x4 acc[2][4];
        #pragma unroll
        for (int i = 0; i < 2; ++i)
            #pragma unroll
            for (int j = 0; j < 4; ++j) acc[i][j] = (f32x4){0.f, 0.f, 0.f, 0.f};

        #pragma unroll
        for (int kc = 0; kc < 8; ++kc) {
            // issue next tile's loads into buf[(kc+1)&1] (prefetch dist 1)
            if (kc < 7) {
                int off = ct * 32768 + (kc + 1) * 32;
                gload_lds16(srcA + off, dstA + ((kc + 1) & 1) * 4096);
                gload_lds16(srcB + off, dstB + ((kc + 1) & 1) * 4096);
            } else if (ct < 31) {
                int off = (ct + 1) * 32768;
                gload_lds16(srcA + off, dstA + ((kc + 1) & 1) * 4096);
                gload_lds16(srcB + off, dstB + ((kc + 1) & 1) * 4096);
            }

            // current tile: 4 x ds_read_b128 + 8 MFMA
            f16x8 fb[4];
            #pragma unroll
            for (int nt = 0; nt < 4; ++nt)
                fb[nt] = *(const f16x8*)(btb + (kc & 1) * 8192 + boffs + nt * 1024);
            #pragma unroll
            for (int mt = 0; mt < 2; ++mt)
                #pragma unroll
                for (int nt = 0; nt < 4; ++nt)
                    acc[mt][nt] = __builtin_amdgcn_mfma_f32_16x16x32_f16(
                        fa[kc][mt], fb[nt], acc[mt][nt], 0, 0, 0);

            // epilogue fills the prefetch-drain latency before the barrier
            if (kc == 7) {
                const int C0 = ct * 128;
                #pragma unroll
                for (int nt = 0; nt < 4; ++nt) {
                    int col = C0 + wn * 64 + nt * 16 + ln;
                    float bn = BnpL[col];
                    #pragma unroll
                    for (int mt = 0; mt < 2; ++mt) {
                        f32x4 a = acc[mt][nt];
                        #pragma unroll
                        for (int r = 0; r < 4; ++r) {
                            float s = fmaf(-4.8828125e-4f, a[r], bn);   // -2^-11 exact
                            int ii = mt * 4 + r;
                            // bit-equivalent to: if(s<b1){b2=b1;b1=s;idx=col}
                            //                    else if(s<b2) b2=s;
                            bool lt = s < best1[ii];
                            best2[ii] = __builtin_amdgcn_fmed3f(best1[ii], best2[ii], s);
                            bidx[ii]  = lt ? col : bidx[ii];
                            best1[ii] = fminf(best1[ii], s);
                        }
                    }
                }
            }
            __syncthreads();   // drains gll (vmcnt) -> next buffer ready
        }
    }

    // merge across the 16 ln-lanes (same rows, different cols); '<'+idx keeps np rule
    #pragma unroll
    for (int mask = 1; mask < 16; mask <<= 1) {
        #pragma unroll
        for (int ii = 0; ii < 8; ++ii) {
            float c1 = __shfl_xor(best1[ii], mask);
            float c2 = __shfl_xor(best2[ii], mask);
            int   ci = __shfl_xor(bidx[ii], mask);
            if (c1 < best1[ii] || (c1 == best1[ii] && ci < bidx[ii])) {
                best2[ii] = fminf(best1[ii], c2);
                best1[ii] = c1; bidx[ii] = ci;
            } else {
                best2[ii] = fminf(best2[ii], c1);
            }
        }
    }
    __syncthreads();   // reuse LDS (Bnp area) for cross-wave merge
    float* mb1 = (float*)lds;          // [64][2]
    float* mb2 = mb1 + 128;
    int*   mix = (int*)(mb2 + 128);
    if (ln == 0) {
        #pragma unroll
        for (int mt = 0; mt < 2; ++mt)
            #pragma unroll
            for (int r = 0; r < 4; ++r) {
                int row = wm * 32 + mt * 16 + qd * 4 + r;
                mb1[row * 2 + wn] = best1[mt * 4 + r];
                mb2[row * 2 + wn] = best2[mt * 4 + r];
                mix[row * 2 + wn] = bidx[mt * 4 + r];
            }
    }
    __syncthreads();
    if (tid < MT) {
        int r = tid;
        float b1 = mb1[r * 2], b2v = mb2[r * 2]; int ix = mix[r * 2];
        float c1 = mb1[r * 2 + 1], c2 = mb2[r * 2 + 1]; int ci = mix[r * 2 + 1];
        if (c1 < b1 || (c1 == b1 && ci < ix)) { b2v = fminf(b1, c2); b1 = c1; ix = ci; }
        else b2v = fminf(b2v, c1);
        idxArr[R0 + r] = ix;
        rowMin[R0 + r] = b1;
        rowKey[R0 + r] = ~0ULL;
        if (b2v - b1 <= DELTA) {
            int p = atomicAdd(flagCnt, 1);
            flagList[p] = R0 + r;
        }
    }
}

// ---------------------------------------------------------------------------
// K4 (stage B): flagged-row rescan, fp32, K-split by blockIdx.y.
// Appends every code with s~ <= rowMin + DELTA as a candidate.
__global__ __launch_bounds__(256, 2)
void stageB(const float* __restrict__ z, const float* __restrict__ cb,
            const float* __restrict__ Bnp, const float* __restrict__ rowMin,
            const int* __restrict__ flagCnt, const int* __restrict__ flagList,
            int* __restrict__ candCnt, unsigned int* __restrict__ candList) {
    __shared__ float smem[2 * DK * LDSP];
    __shared__ int   frow[BMT];
    __shared__ float rmin[BMT];
    float (*zt)[LDSP] = (float (*)[LDSP])smem;
    float (*ct)[LDSP] = (float (*)[LDSP])(smem + DK * LDSP);

    const int nf = *flagCnt;
    const int R0 = blockIdx.x * BMT;
    if (R0 >= nf) return;
    const int m = min(BMT, nf - R0);

    const int tid = threadIdx.x;
    const int tx  = tid & 15;
    const int ty  = tid >> 4;

    if (tid < BMT) {
        int fr = flagList[R0 + min(tid, m - 1)];   // pad w/ last real row (dups harmless)
        frow[tid] = fr;
        rmin[tid] = rowMin[fr];
    }
    __syncthreads();

    int   grr[8];
    float rm[8];
    #pragma unroll
    for (int i = 0; i < 8; ++i) { grr[i] = frow[ty * 8 + i]; rm[i] = rmin[ty * 8 + i]; }

    const int ktBeg = blockIdx.y * (NE / NSPLIT);
    const int ktEnd = ktBeg + NE / NSPLIT;
    for (int kt = ktBeg; kt < ktEnd; kt += KT) {
        float acc[8][8];
        #pragma unroll
        for (int i = 0; i < 8; ++i)
            #pragma unroll
            for (int j = 0; j < 8; ++j) acc[i][j] = 0.f;

        for (int d0 = 0; d0 < D; d0 += DK) {
            __syncthreads();
            #pragma unroll
            for (int it = 0; it < 4; ++it) {
                int q  = tid + 256 * it;
                int r  = q >> 3;
                int dd = (q & 7) << 2;
                float4 zv = *(const float4*)(z  + (size_t)frow[r] * D + d0 + dd);
                float4 cv = *(const float4*)(cb + (size_t)(kt + r) * D + d0 + dd);
                zt[dd + 0][r] = zv.x; zt[dd + 1][r] = zv.y;
                zt[dd + 2][r] = zv.z; zt[dd + 3][r] = zv.w;
                ct[dd + 0][r] = cv.x; ct[dd + 1][r] = cv.y;
                ct[dd + 2][r] = cv.z; ct[dd + 3][r] = cv.w;
            }
            __syncthreads();
            #pragma unroll 4
            for (int dd = 0; dd < DK; ++dd) {
                float4 za = *(const float4*)&zt[dd][ty * 8];
                float4 zb = *(const float4*)&zt[dd][ty * 8 + 4];
                float4 ca = *(const float4*)&ct[dd][tx * 8];
                float4 cc = *(const float4*)&ct[dd][tx * 8 + 4];
                float zf[8] = {za.x, za.y, za.z, za.w, zb.x, zb.y, zb.z, zb.w};
                float cf[8] = {ca.x, ca.y, ca.z, ca.w, cc.x, cc.y, cc.z, cc.w};
                #pragma unroll
                for (int i = 0; i < 8; ++i)
                    #pragma unroll
                    for (int j = 0; j < 8; ++j)
                        acc[i][j] = fmaf(zf[i], cf[j], acc[i][j]);
            }
        }
        const int cbase = kt + tx * 8;
        float4 ea = *(const float4*)(Bnp + cbase);
        float4 eb = *(const float4*)(Bnp + cbase + 4);
        float e2v[8] = {ea.x, ea.y, ea.z, ea.w, eb.x, eb.y, eb.z, eb.w};
        #pragma unroll
        for (int i = 0; i < 8; ++i) {
            #pragma unroll
            for (int j = 0; j < 8; ++j) {
                float s = fmaf(-2.f, acc[i][j], e2v[j]);
                if (s <= rm[i] + DELTA) {
                    int p = atomicAdd(candCnt, 1);
                    if (p < CAND_CAP)
                        candList[p] = ((unsigned)grr[i] << 12) | (unsigned)(cbase + j);
                }
            }
        }
    }
}

// ---------------------------------------------------------------------------
// K5 (stage C): bit-exact numpy score per candidate (||z||^2 computed inline),
// folded via atomicMin((fp32 bits << 32) | k) = np's min-then-lowest-idx rule.
__global__ void stageC(const float* __restrict__ z, const float* __restrict__ cb,
                       const float* __restrict__ Bnp,
                       const int* __restrict__ candCnt,
                       const unsigned int* __restrict__ candList,
                       unsigned long long* __restrict__ rowKey) {
    int c = blockIdx.x * 256 + threadIdx.x;
    int n = min(*candCnt, CAND_CAP);
    if (c >= n) return;
    unsigned e = candList[c];
    int r = (int)(e >> 12);
    int k = (int)(e & 4095u);
    float Anp = np_sumsq256(z + (size_t)r * D);
    float C   = np_einsum_dot256(z + (size_t)r * D, cb + (size_t)k * D);
    float AB  = __fadd_rn(Anp, Bnp[k]);
    float s   = __fsub_rn(AB, __fadd_rn(C, C));
    unsigned long long key = ((unsigned long long)__float_as_uint(s) << 32) | (unsigned)k;
    atomicMin(rowKey + r, key);
}

// ---------------------------------------------------------------------------
// K6: gather out[r] = cb[idx]; idx from rowKey override (flagged) or idxArr.
__global__ void gather_kernel(const float* __restrict__ cb,
                              const int* __restrict__ idxArr,
                              const unsigned long long* __restrict__ rowKey,
                              float* __restrict__ out) {
    int r = blockIdx.x * 4 + (threadIdx.x >> 6);
    int l = threadIdx.x & 63;
    unsigned long long kv = rowKey[r];
    int ix = (kv != ~0ULL) ? (int)(kv & 0xFFFFFFFFull) : idxArr[r];
    *(float4*)(out + (size_t)r * D + l * 4) =
        *(const float4*)(cb + (size_t)ix * D + l * 4);
}

// ---------------------------------------------------------------------------
extern "C" void kernel_launch(void* const* d_in, const int* in_sizes, int n_in,
                              void* d_out, int out_size, void* d_ws, size_t ws_size,
                              hipStream_t stream) {
    const float* z  = (const float*)d_in[0];
    const float* cb = (const float*)d_in[1];
    float* out = (float*)d_out;
    const int nRows = in_sizes[0] / D;   // 65536

    char* w = (char*)d_ws;
    unsigned short* z2  = (unsigned short*)w;                         // 32 MB fp16
    unsigned short* cb2 = (unsigned short*)(w + 33554432);            // 2 MB fp16 (x4096)
    unsigned long long* rowKey = (unsigned long long*)(w + 35651584); // 512 KB
    int*   idxArr   = (int*)  (w + 36175872);                         // 256 KB
    float* rowMin   = (float*)(w + 36438016);                         // 256 KB
    int*   flagList = (int*)  (w + 36700160);                         // 256 KB
    float* Bnp      = (float*)(w + 36962304);                         // 16 KB
    unsigned int* candList = (unsigned int*)(w + 36978688);           // 512 KB
    int*   flagCnt  = (int*)  (w + 37502976);
    int*   candCnt  = flagCnt + 1;

    hipMemsetAsync(flagCnt, 0, 8, stream);
    bnp_kernel<<<NE / 256, 256, 0, stream>>>(cb, Bnp);
    tof16_kernel<<<nRows * 64 / 256, 256, 0, stream>>>(z, z2, 1.0f, nRows * 64);
    tof16_kernel<<<NE * 64 / 256, 256, 0, stream>>>(cb, cb2, 4096.0f, NE * 64);
    stageA_f16<<<nRows / MT, 256, 0, stream>>>(z2, cb2, Bnp, idxArr, rowMin,
                                               rowKey, flagCnt, flagList);
    stageB<<<dim3(nRows / BMT, NSPLIT), 256, 0, stream>>>(z, cb, Bnp, rowMin,
                                                          flagCnt, flagList,
                                                          candCnt, candList);
    stageC<<<CAND_CAP / 256, 256, 0, stream>>>(z, cb, Bnp, candCnt, candList, rowKey);
    gather_kernel<<<nRows / 4, 256, 0, stream>>>(cb, idxArr, rowKey, out);
}

// Round 3
// 444.954 us; speedup vs baseline: 1.7598x; 1.4134x over previous
//
#include <hip/hip_runtime.h>
#include <hip/hip_fp16.h>
#include <cfloat>
#include <climits>

// VectorQuantizer2: z [32,2048,256] fp32, codebook [4096,256] fp32.
#define D     256
#define NE    4096
#define MT    64       // rows per block (stageA)
#define NSPLITB 8      // stageB K-split factor (512 codes per block)
// DELTA covers worst-case np fp32 envelope (2*4.6e-5) + fp16 single-pass dot
// worst bound (~5e-5 score). stageB hi/lo-MFMA error (~1e-7) is negligible.
#define DELTA     1.5e-4f
#define CAND_CAP  131072

typedef _Float16 f16x8 __attribute__((ext_vector_type(8)));
typedef __attribute__((ext_vector_type(4))) float f32x4;

// counted-vmcnt barrier: keep prefetch in flight across the barrier (T4).
// Fused in ONE asm so no memory op can slip between wait and barrier.
// sched_barrier(0) after it pins every LDS read AFTER the wait (rule-18 class).
#define SYNC(n) do { \
    asm volatile("s_waitcnt vmcnt(" #n ")\n\ts_barrier" ::: "memory"); \
    __builtin_amdgcn_sched_barrier(0); \
} while (0)

// ---------------------------------------------------------------------------
// numpy-bit-exact fp32 helpers. __fmul_rn/__fadd_rn are contraction barriers.
__device__ __forceinline__ float np_block128_sq(const float* __restrict__ p) {
    float r[8];
    #pragma unroll
    for (int j = 0; j < 8; ++j) r[j] = __fmul_rn(p[j], p[j]);
    #pragma unroll
    for (int i = 8; i < 128; i += 8)
        #pragma unroll
        for (int j = 0; j < 8; ++j) r[j] = __fadd_rn(r[j], __fmul_rn(p[i + j], p[i + j]));
    return __fadd_rn(__fadd_rn(__fadd_rn(r[0], r[1]), __fadd_rn(r[2], r[3])),
                     __fadd_rn(__fadd_rn(r[4], r[5]), __fadd_rn(r[6], r[7])));
}
__device__ __forceinline__ float np_sumsq256(const float* __restrict__ p) {
    return __fadd_rn(np_block128_sq(p), np_block128_sq(p + 128));
}
// np.einsum('nd,kd->nk', optimize=False) dot: SSE 4-lane, no FMA, 16/iter,
// chained muladd order p3,p2,p1,p0, SSE3 hadd (v0+v1)+(v2+v3).
__device__ __forceinline__ float np_einsum_dot256(const float* __restrict__ zr,
                                                  const float* __restrict__ er) {
    float v0 = 0.f, v1 = 0.f, v2 = 0.f, v3 = 0.f;
    for (int t = 0; t < 256; t += 16) {
        float4 a0 = *(const float4*)(zr + t);
        float4 a1 = *(const float4*)(zr + t + 4);
        float4 a2 = *(const float4*)(zr + t + 8);
        float4 a3 = *(const float4*)(zr + t + 12);
        float4 b0 = *(const float4*)(er + t);
        float4 b1 = *(const float4*)(er + t + 4);
        float4 b2 = *(const float4*)(er + t + 8);
        float4 b3 = *(const float4*)(er + t + 12);
        v0 = __fadd_rn(v0, __fmul_rn(a3.x, b3.x));
        v1 = __fadd_rn(v1, __fmul_rn(a3.y, b3.y));
        v2 = __fadd_rn(v2, __fmul_rn(a3.z, b3.z));
        v3 = __fadd_rn(v3, __fmul_rn(a3.w, b3.w));
        v0 = __fadd_rn(v0, __fmul_rn(a2.x, b2.x));
        v1 = __fadd_rn(v1, __fmul_rn(a2.y, b2.y));
        v2 = __fadd_rn(v2, __fmul_rn(a2.z, b2.z));
        v3 = __fadd_rn(v3, __fmul_rn(a2.w, b2.w));
        v0 = __fadd_rn(v0, __fmul_rn(a1.x, b1.x));
        v1 = __fadd_rn(v1, __fmul_rn(a1.y, b1.y));
        v2 = __fadd_rn(v2, __fmul_rn(a1.z, b1.z));
        v3 = __fadd_rn(v3, __fmul_rn(a1.w, b1.w));
        v0 = __fadd_rn(v0, __fmul_rn(a0.x, b0.x));
        v1 = __fadd_rn(v1, __fmul_rn(a0.y, b0.y));
        v2 = __fadd_rn(v2, __fmul_rn(a0.z, b0.z));
        v3 = __fadd_rn(v3, __fmul_rn(a0.w, b0.w));
    }
    return __fadd_rn(__fadd_rn(v0, v1), __fadd_rn(v2, v3));
}

// ---------------------------------------------------------------------------
// K1: Bnp[k] = np-exact sum(cb[k]**2)
__global__ void bnp_kernel(const float* __restrict__ cb, float* __restrict__ Bnp) {
    int k = blockIdx.x * 256 + threadIdx.x;
    if (k < NE) Bnp[k] = np_sumsq256(cb + (size_t)k * D);
}

// K2: codebook -> fp16 hi/lo pair.  E = 4096*cb (exact pow2);
// hi = RN16(E); lo = RN16((E - hi) * 2048).
__global__ void cbhl_kernel(const float* __restrict__ cb,
                            unsigned short* __restrict__ hi,
                            unsigned short* __restrict__ lo) {
    int t = blockIdx.x * 256 + threadIdx.x;          // NE*D/4 = 262144 float4s
    float4 v = *(const float4*)(cb + (size_t)t * 4);
    float e[4] = {v.x * 4096.f, v.y * 4096.f, v.z * 4096.f, v.w * 4096.f};
    ushort4 H, L;
    unsigned short* Hp = (unsigned short*)&H;
    unsigned short* Lp = (unsigned short*)&L;
    #pragma unroll
    for (int j = 0; j < 4; ++j) {
        _Float16 hh = (_Float16)e[j];
        _Float16 ll = (_Float16)((e[j] - (float)hh) * 2048.0f);
        Hp[j] = __builtin_bit_cast(unsigned short, hh);
        Lp[j] = __builtin_bit_cast(unsigned short, ll);
    }
    *(ushort4*)(hi + (size_t)t * 4) = H;
    *(ushort4*)(lo + (size_t)t * 4) = L;
}

// direct global->LDS 16B (dwordx4). LDS dest must be wave-uniform base;
// HW writes lane i at base + 16*i. Global source is per-lane.
__device__ __forceinline__ void gload_lds16(const void* g, void* l) {
    __builtin_amdgcn_global_load_lds(
        (const __attribute__((address_space(1))) unsigned int*)g,
        (__attribute__((address_space(3))) unsigned int*)l, 16, 0, 0);
}

// ---------------------------------------------------------------------------
// K3 (stage A): single-pass fp16 MFMA score GEMM + per-row top-2.
// acc = f16(z) · f16(4096*cb) ;  s = Bnp[k] - 2^-11 * acc.
// Block: 256 thr = 4 waves (2x2), tile 64 rows x 128 codes, wave 32x64.
//   A: fp32 z converted to fp16 regs on the fly in the prologue (no z2 pass).
//   B: 4 LDS buffers, prefetch distance 3, filled by global_load_lds dwordx4.
//      Counted-vmcnt barriers (SYNC(4)) keep 3 tiles in flight ACROSS the
//      barrier -- never drain vmcnt to 0 in the main loop (T3+T4).
//      Loop body has NO VMEM except the gll's, so vmcnt counting is exact.
//   Bank swizzle: source seg ^= (code>>1)&3 pre-applied on the GLOBAL address
//      (LDS dest of gll must stay linear), same XOR on the ds_read side.
__global__ __launch_bounds__(256, 3)
void stageA_f16(const float* __restrict__ z,
                const unsigned short* __restrict__ cb2,
                const float* __restrict__ Bnp, int* __restrict__ idxArr,
                float* __restrict__ rowMin, unsigned long long* __restrict__ rowKey,
                int* __restrict__ flagCnt, int* __restrict__ flagList) {
    __shared__ unsigned char lds[16384 + 4 * 8192];  // Bnp 16K + 4 B-buffers
    float* BnpL = (float*)lds;
    unsigned short* Bt = (unsigned short*)(lds + 16384);

    const int tid  = threadIdx.x;
    const int wid  = tid >> 6;
    const int lane = tid & 63;
    const int ln   = lane & 15;      // col within 16x16 tile
    const int qd   = lane >> 4;      // quad
    const int wm   = wid & 1;        // wave row (32 rows each)
    const int wn   = wid >> 1;       // wave col (64 codes each)
    const int R0   = blockIdx.x * MT;

    // ---- Bnp -> LDS (4096 f32, 4 float4 per thread)
    #pragma unroll
    for (int i = 0; i < 4; ++i) {
        int j = tid + 256 * i;
        *(float4*)(BnpL + j * 4) = *(const float4*)(Bnp + j * 4);
    }

    // ---- A panel -> registers (fp32 -> fp16 RNE on the fly)
    f16x8 fa[8][2];
    {
        const float* za = z + (size_t)(R0 + wm * 32 + ln) * 256 + qd * 8;
        #pragma unroll
        for (int kc = 0; kc < 8; ++kc)
            #pragma unroll
            for (int mt = 0; mt < 2; ++mt) {
                const float* p = za + mt * 16 * 256 + kc * 32;
                float4 a = *(const float4*)p, b = *(const float4*)(p + 4);
                f16x8 h;
                h[0] = (_Float16)a.x; h[1] = (_Float16)a.y;
                h[2] = (_Float16)a.z; h[3] = (_Float16)a.w;
                h[4] = (_Float16)b.x; h[5] = (_Float16)b.y;
                h[6] = (_Float16)b.z; h[7] = (_Float16)b.w;
                fa[kc][mt] = h;
            }
    }

    // ---- B staging map (verified swizzle): lane l of gll j writes slot
    // wid*128 + j*64 + l -> code = wid*32 + j*16 + (l>>2), qslot = l&3.
    // Source seg = qslot ^ ((code>>1)&3).  Note seg-xor is identical for
    // code and code+16, so the second gll is srcA + 16*256 halves.
    const int cA  = wid * 32 + (lane >> 2);
    const int sgA = (lane & 3) ^ ((cA >> 1) & 3);
    const unsigned short* srcA = cb2 + cA * 256 + sgA * 8;
    unsigned short* dstW = Bt + wid * 1024;          // wave-uniform
    // B fragment ds_read byte offset within one buffer (swizzled read side)
    const int boffs = ((wn * 64 + ln) << 6) + ((qd ^ ((ln >> 1) & 3)) << 4);
    const unsigned char* btb = (const unsigned char*)Bt;

    float best1[8], best2[8];
    int   bidx[8];
    #pragma unroll
    for (int i = 0; i < 8; ++i) { best1[i] = FLT_MAX; best2[i] = FLT_MAX; bidx[i] = 0; }

    // ---- prologue: stage steps 0,1,2 into bufs 0,1,2; drain once.
    #pragma unroll
    for (int s = 0; s < 3; ++s) {
        gload_lds16(srcA + s * 32, dstW + s * 4096);
        gload_lds16(srcA + s * 32 + 4096, dstW + s * 4096 + 512);
    }
    __syncthreads();

    // ---- main loop: steps s = ct*8+kc; buf(s) = kc&3; issue s+3 each step.
    for (int ct = 0; ct < 31; ++ct) {
        f32x4 acc[2][4];
        #pragma unroll
        for (int i = 0; i < 2; ++i)
            #pragma unroll
            for (int j = 0; j < 4; ++j) acc[i][j] = (f32x4){0.f, 0.f, 0.f, 0.f};

        #pragma unroll
        for (int kc = 0; kc < 8; ++kc) {
            SYNC(4);    // buf kc&3 ready; prior readers of buf (kc+3)&3 done
            {           // issue step s+3
                const int s3k = kc + 3;
                int off = (ct + (s3k >> 3)) * 32768 + (s3k & 7) * 32;
                unsigned short* d = dstW + ((s3k & 3) << 12);
                gload_lds16(srcA + off, d);
                gload_lds16(srcA + off + 4096, d + 512);
            }
            f16x8 fb[4];
            #pragma unroll
            for (int nt = 0; nt < 4; ++nt)
                fb[nt] = *(const f16x8*)(btb + ((kc & 3) << 13) + boffs + nt * 1024);
            __builtin_amdgcn_s_setprio(1);
            #pragma unroll
            for (int mt = 0; mt < 2; ++mt)
                #pragma unroll
                for (int nt = 0; nt < 4; ++nt)
                    acc[mt][nt] = __builtin_amdgcn_mfma_f32_16x16x32_f16(
                        fa[kc][mt], fb[nt], acc[mt][nt], 0, 0, 0);
            __builtin_amdgcn_s_setprio(0);

            if (kc == 7) {   // epilogue: fold scores into per-lane top-2
                const int C0 = ct * 128;
                #pragma unroll
                for (int nt = 0; nt < 4; ++nt) {
                    int col = C0 + wn * 64 + nt * 16 + ln;
                    float bn = BnpL[col];
                    #pragma unroll
                    for (int mt = 0; mt < 2; ++mt) {
                        f32x4 a = acc[mt][nt];
                        #pragma unroll
                        for (int r = 0; r < 4; ++r) {
                            float s = fmaf(-4.8828125e-4f, a[r], bn);   // -2^-11
                            int ii = mt * 4 + r;
                            bool lt = s < best1[ii];
                            best2[ii] = __builtin_amdgcn_fmed3f(best1[ii], best2[ii], s);
                            bidx[ii]  = lt ? col : bidx[ii];
                            best1[ii] = fminf(best1[ii], s);
                        }
                    }
                }
            }
        }
    }
    // ---- tail ct = 31 (steps 248..255): wind down the pipeline.
    {
        const int ct = 31;
        f32x4 acc[2][4];
        #pragma unroll
        for (int i = 0; i < 2; ++i)
            #pragma unroll
            for (int j = 0; j < 4; ++j) acc[i][j] = (f32x4){0.f, 0.f, 0.f, 0.f};

        #pragma unroll
        for (int kc = 0; kc < 8; ++kc) {
            if (kc <= 5) { SYNC(4); } else if (kc == 6) { SYNC(2); } else { SYNC(0); }
            if (kc <= 4) {
                const int s3k = kc + 3;
                int off = ct * 32768 + (s3k & 7) * 32;
                unsigned short* d = dstW + ((s3k & 3) << 12);
                gload_lds16(srcA + off, d);
                gload_lds16(srcA + off + 4096, d + 512);
            }
            f16x8 fb[4];
            #pragma unroll
            for (int nt = 0; nt < 4; ++nt)
                fb[nt] = *(const f16x8*)(btb + ((kc & 3) << 13) + boffs + nt * 1024);
            __builtin_amdgcn_s_setprio(1);
            #pragma unroll
            for (int mt = 0; mt < 2; ++mt)
                #pragma unroll
                for (int nt = 0; nt < 4; ++nt)
                    acc[mt][nt] = __builtin_amdgcn_mfma_f32_16x16x32_f16(
                        fa[kc][mt], fb[nt], acc[mt][nt], 0, 0, 0);
            __builtin_amdgcn_s_setprio(0);

            if (kc == 7) {
                const int C0 = ct * 128;
                #pragma unroll
                for (int nt = 0; nt < 4; ++nt) {
                    int col = C0 + wn * 64 + nt * 16 + ln;
                    float bn = BnpL[col];
                    #pragma unroll
                    for (int mt = 0; mt < 2; ++mt) {
                        f32x4 a = acc[mt][nt];
                        #pragma unroll
                        for (int r = 0; r < 4; ++r) {
                            float s = fmaf(-4.8828125e-4f, a[r], bn);
                            int ii = mt * 4 + r;
                            bool lt = s < best1[ii];
                            best2[ii] = __builtin_amdgcn_fmed3f(best1[ii], best2[ii], s);
                            bidx[ii]  = lt ? col : bidx[ii];
                            best1[ii] = fminf(best1[ii], s);
                        }
                    }
                }
            }
        }
    }

    // merge across the 16 ln-lanes (same rows, different cols); '<'+idx keeps np rule
    #pragma unroll
    for (int mask = 1; mask < 16; mask <<= 1) {
        #pragma unroll
        for (int ii = 0; ii < 8; ++ii) {
            float c1 = __shfl_xor(best1[ii], mask);
            float c2 = __shfl_xor(best2[ii], mask);
            int   ci = __shfl_xor(bidx[ii], mask);
            if (c1 < best1[ii] || (c1 == best1[ii] && ci < bidx[ii])) {
                best2[ii] = fminf(best1[ii], c2);
                best1[ii] = c1; bidx[ii] = ci;
            } else {
                best2[ii] = fminf(best2[ii], c1);
            }
        }
    }
    __syncthreads();   // reuse LDS (Bnp area) for cross-wave merge
    float* mb1 = (float*)lds;          // [64][2]
    float* mb2 = mb1 + 128;
    int*   mix = (int*)(mb2 + 128);
    if (ln == 0) {
        #pragma unroll
        for (int mt = 0; mt < 2; ++mt)
            #pragma unroll
            for (int r = 0; r < 4; ++r) {
                int row = wm * 32 + mt * 16 + qd * 4 + r;
                mb1[row * 2 + wn] = best1[mt * 4 + r];
                mb2[row * 2 + wn] = best2[mt * 4 + r];
                mix[row * 2 + wn] = bidx[mt * 4 + r];
            }
    }
    __syncthreads();
    if (tid < MT) {
        int r = tid;
        float b1 = mb1[r * 2], b2v = mb2[r * 2]; int ix = mix[r * 2];
        float c1 = mb1[r * 2 + 1], c2 = mb2[r * 2 + 1]; int ci = mix[r * 2 + 1];
        if (c1 < b1 || (c1 == b1 && ci < ix)) { b2v = fminf(b1, c2); b1 = c1; ix = ci; }
        else b2v = fminf(b2v, c1);
        idxArr[R0 + r] = ix;
        rowMin[R0 + r] = b1;
        rowKey[R0 + r] = ~0ULL;
        if (b2v - b1 <= DELTA) {
            int p = atomicAdd(flagCnt, 1);
            flagList[p] = R0 + r;
        }
    }
}

// ---------------------------------------------------------------------------
// K4 (stage B): flagged-row rescan via fp16 hi/lo MFMA (3 passes):
//   z·E = zh·Eh + 2^-11 (zh·El + zl·Eh) + O(2^-22)   (residual ~4e-8 score)
//   s = Bnp[k] - 2^-11*acc1 - 2^-22*acc2
// Block 256 thr = 4 waves (2x2): tile 32 rows x 128 codes, wave 16x64
// (mt=1, nt=4).  3 LDS buffers (hi||lo), prefetch distance 2, SYNC(4).
// Hits recorded in a 64-bit mask, emitted AFTER the loop (keeps the loop
// free of VMEM so the counted vmcnt stays exact).  K-split over blockIdx.y.
__global__ __launch_bounds__(256, 3)
void stageB_f16(const float* __restrict__ z,
                const unsigned short* __restrict__ cb2,
                const unsigned short* __restrict__ cbl2,
                const float* __restrict__ Bnp, const float* __restrict__ rowMin,
                const int* __restrict__ flagCnt, const int* __restrict__ flagList,
                int* __restrict__ candCnt, unsigned int* __restrict__ candList) {
    __shared__ unsigned char lds[3 * 16384 + 256];   // 3 bufs (8K hi + 8K lo)
    unsigned short* Bt = (unsigned short*)lds;
    int*   frow   = (int*)(lds + 49152);
    float* rmin_l = (float*)(lds + 49152 + 128);

    const int nf = *flagCnt;
    const int R0 = blockIdx.x * 32;
    if (R0 >= nf) return;
    const int m = min(32, nf - R0);

    const int tid  = threadIdx.x;
    const int wid  = tid >> 6;
    const int lane = tid & 63;
    const int ln   = lane & 15;
    const int qd   = lane >> 4;
    const int wm   = wid & 1;        // wave row group (16 rows each)
    const int wn   = wid >> 1;       // wave col group (64 codes each)
    const int ktBeg = blockIdx.y * (NE / NSPLITB);   // 512 codes per block

    if (tid < 32) {
        int fr = flagList[R0 + min(tid, m - 1)];   // pad w/ last row (dups harmless)
        frow[tid] = fr;
        rmin_l[tid] = rowMin[fr];
    }
    __syncthreads();

    int grr_[4]; float rmv[4];
    #pragma unroll
    for (int r = 0; r < 4; ++r) {
        int rl = wm * 16 + qd * 4 + r;
        grr_[r] = frow[rl];
        rmv[r]  = rmin_l[rl];
    }
    const int rowA = frow[wm * 16 + ln];

    // Bnp for this block's code range -> regs (all-static indexing)
    float bnv[4][4];
    #pragma unroll
    for (int ct = 0; ct < 4; ++ct)
        #pragma unroll
        for (int nt = 0; nt < 4; ++nt)
            bnv[ct][nt] = Bnp[ktBeg + ct * 128 + wn * 64 + nt * 16 + ln];

    // A row -> fp16 hi/lo regs on the fly
    f16x8 fah[8], fal[8];
    {
        const float* za = z + (size_t)rowA * 256 + qd * 8;
        #pragma unroll
        for (int kc = 0; kc < 8; ++kc) {
            const float* p = za + kc * 32;
            float4 a = *(const float4*)p, b = *(const float4*)(p + 4);
            float x[8] = {a.x, a.y, a.z, a.w, b.x, b.y, b.z, b.w};
            f16x8 h, l;
            #pragma unroll
            for (int j = 0; j < 8; ++j) {
                _Float16 hh = (_Float16)x[j];
                h[j] = hh;
                l[j] = (_Float16)((x[j] - (float)hh) * 2048.0f);
            }
            fah[kc] = h; fal[kc] = l;
        }
    }

    // B staging map (same verified swizzle as stageA)
    const int cA  = wid * 32 + (lane >> 2);
    const int sgA = (lane & 3) ^ ((cA >> 1) & 3);
    const unsigned short* srcH = cb2  + (size_t)(ktBeg + cA) * 256 + sgA * 8;
    const unsigned short* srcL = cbl2 + (size_t)(ktBeg + cA) * 256 + sgA * 8;
    unsigned short* dstW = Bt + wid * 1024;
    const int boffs = ((wn * 64 + ln) << 6) + ((qd ^ ((ln >> 1) & 3)) << 4);
    const unsigned char* btb = (const unsigned char*)Bt;

    // prologue: stage steps 0,1 into bufs 0,1; drain once.
    #pragma unroll
    for (int s = 0; s < 2; ++s) {
        unsigned short* d = dstW + s * 8192;
        gload_lds16(srcH + s * 32, d);
        gload_lds16(srcH + s * 32 + 4096, d + 512);
        gload_lds16(srcL + s * 32, d + 4096);
        gload_lds16(srcL + s * 32 + 4096, d + 4096 + 512);
    }
    __syncthreads();

    unsigned long long hm = 0;   // hit mask: bit = ct*16 + nt*4 + r

    #pragma unroll
    for (int ct = 0; ct < 4; ++ct) {
        f32x4 a1[4], a2[4];
        #pragma unroll
        for (int j = 0; j < 4; ++j) {
            a1[j] = (f32x4){0.f, 0.f, 0.f, 0.f};
            a2[j] = (f32x4){0.f, 0.f, 0.f, 0.f};
        }
        #pragma unroll
        for (int kc = 0; kc < 8; ++kc) {
            const int s = ct * 8 + kc;
            if (s < 31) { SYNC(4); } else { SYNC(0); }
            if (s + 2 <= 31) {
                const int s2 = s + 2;
                int off = (s2 >> 3) * 32768 + (s2 & 7) * 32;
                unsigned short* d = dstW + (s2 % 3) * 8192;
                gload_lds16(srcH + off, d);
                gload_lds16(srcH + off + 4096, d + 512);
                gload_lds16(srcL + off, d + 4096);
                gload_lds16(srcL + off + 4096, d + 4096 + 512);
            }
            const int bb = (s % 3) * 16384;
            f16x8 fbh[4], fbl[4];
            #pragma unroll
            for (int nt = 0; nt < 4; ++nt) {
                fbh[nt] = *(const f16x8*)(btb + bb + boffs + nt * 1024);
                fbl[nt] = *(const f16x8*)(btb + bb + 8192 + boffs + nt * 1024);
            }
            __builtin_amdgcn_s_setprio(1);
            #pragma unroll
            for (int nt = 0; nt < 4; ++nt)
                a1[nt] = __builtin_amdgcn_mfma_f32_16x16x32_f16(fah[kc], fbh[nt], a1[nt], 0, 0, 0);
            #pragma unroll
            for (int nt = 0; nt < 4; ++nt)
                a2[nt] = __builtin_amdgcn_mfma_f32_16x16x32_f16(fah[kc], fbl[nt], a2[nt], 0, 0, 0);
            #pragma unroll
            for (int nt = 0; nt < 4; ++nt)
                a2[nt] = __builtin_amdgcn_mfma_f32_16x16x32_f16(fal[kc], fbh[nt], a2[nt], 0, 0, 0);
            __builtin_amdgcn_s_setprio(0);

            if (kc == 7) {
                #pragma unroll
                for (int nt = 0; nt < 4; ++nt)
                    #pragma unroll
                    for (int r = 0; r < 4; ++r) {
                        float s1 = fmaf(-4.8828125e-4f, a1[nt][r], bnv[ct][nt]);
                        float sc = fmaf(-2.384185791015625e-7f, a2[nt][r], s1);
                        if (sc <= rmv[r] + DELTA)
                            hm |= 1ull << (ct * 16 + nt * 4 + r);
                    }
            }
        }
    }

    // rare-path emission (post-loop; VMEM allowed here)
    while (hm) {
        int b = __builtin_ctzll(hm);
        hm &= hm - 1;
        int ctb = b >> 4, ntb = (b >> 2) & 3, rb = b & 3;
        int col = ktBeg + ctb * 128 + wn * 64 + ntb * 16 + ln;
        int rr  = (rb == 0) ? grr_[0] : (rb == 1) ? grr_[1] : (rb == 2) ? grr_[2] : grr_[3];
        int p = atomicAdd(candCnt, 1);
        if (p < CAND_CAP)
            candList[p] = ((unsigned)rr << 12) | (unsigned)col;
    }
}

// ---------------------------------------------------------------------------
// K5 (stage C): bit-exact numpy score per candidate (||z||^2 computed inline),
// folded via atomicMin((fp32 bits << 32) | k) = np's min-then-lowest-idx rule.
__global__ void stageC(const float* __restrict__ z, const float* __restrict__ cb,
                       const float* __restrict__ Bnp,
                       const int* __restrict__ candCnt,
                       const unsigned int* __restrict__ candList,
                       unsigned long long* __restrict__ rowKey) {
    int c = blockIdx.x * 256 + threadIdx.x;
    int n = min(*candCnt, CAND_CAP);
    if (c >= n) return;
    unsigned e = candList[c];
    int r = (int)(e >> 12);
    int k = (int)(e & 4095u);
    float Anp = np_sumsq256(z + (size_t)r * D);
    float C   = np_einsum_dot256(z + (size_t)r * D, cb + (size_t)k * D);
    float AB  = __fadd_rn(Anp, Bnp[k]);
    float s   = __fsub_rn(AB, __fadd_rn(C, C));
    unsigned long long key = ((unsigned long long)__float_as_uint(s) << 32) | (unsigned)k;
    atomicMin(rowKey + r, key);
}

// ---------------------------------------------------------------------------
// K6: gather out[r] = cb[idx]; idx from rowKey override (flagged) or idxArr.
__global__ void gather_kernel(const float* __restrict__ cb,
                              const int* __restrict__ idxArr,
                              const unsigned long long* __restrict__ rowKey,
                              float* __restrict__ out) {
    int r = blockIdx.x * 4 + (threadIdx.x >> 6);
    int l = threadIdx.x & 63;
    unsigned long long kv = rowKey[r];
    int ix = (kv != ~0ULL) ? (int)(kv & 0xFFFFFFFFull) : idxArr[r];
    *(float4*)(out + (size_t)r * D + l * 4) =
        *(const float4*)(cb + (size_t)ix * D + l * 4);
}

// ---------------------------------------------------------------------------
extern "C" void kernel_launch(void* const* d_in, const int* in_sizes, int n_in,
                              void* d_out, int out_size, void* d_ws, size_t ws_size,
                              hipStream_t stream) {
    const float* z  = (const float*)d_in[0];
    const float* cb = (const float*)d_in[1];
    float* out = (float*)d_out;
    const int nRows = in_sizes[0] / D;   // 65536

    char* w = (char*)d_ws;
    unsigned short* cb2  = (unsigned short*)w;                        // 2 MB hi
    unsigned short* cbl2 = (unsigned short*)(w + 2097152);            // 2 MB lo
    unsigned long long* rowKey = (unsigned long long*)(w + 4194304);  // 512 KB
    int*   idxArr   = (int*)  (w + 4718592);                          // 256 KB
    float* rowMin   = (float*)(w + 4980736);                          // 256 KB
    int*   flagList = (int*)  (w + 5242880);                          // 256 KB
    float* Bnp      = (float*)(w + 5505024);                          // 16 KB
    unsigned int* candList = (unsigned int*)(w + 5521408);            // 512 KB
    int*   flagCnt  = (int*)  (w + 6045696);
    int*   candCnt  = flagCnt + 1;

    hipMemsetAsync(flagCnt, 0, 8, stream);
    bnp_kernel<<<NE / 256, 256, 0, stream>>>(cb, Bnp);
    cbhl_kernel<<<NE * D / 4 / 256, 256, 0, stream>>>(cb, cb2, cbl2);
    stageA_f16<<<nRows / MT, 256, 0, stream>>>(z, cb2, Bnp, idxArr, rowMin,
                                               rowKey, flagCnt, flagList);
    stageB_f16<<<dim3(nRows / 32, NSPLITB), 256, 0, stream>>>(z, cb2, cbl2, Bnp,
                                                              rowMin, flagCnt, flagList,
                                                              candCnt, candList);
    stageC<<<CAND_CAP / 256, 256, 0, stream>>>(z, cb, Bnp, candCnt, candList, rowKey);
    gather_kernel<<<nRows / 4, 256, 0, stream>>>(cb, idxArr, rowKey, out);
}